// Round 1
// baseline (296.718 us; speedup 1.0000x reference)
//
#include <hip/hip_runtime.h>
#include <stdint.h>

#define TPB   256
#define D_DIM 4096
#define EPW   16      // elements per thread = D/TPB
#define NBIN  1024
#define CAP   512
#define KSEL  16

struct SMem {
    union {
        unsigned int hist[NBIN];               // 4 KB (pass 1)
        unsigned long long lists[2 * CAP];     // 8 KB (pass 2): [0,CAP)=top, [CAP,2CAP)=bot
    } u;
    float red[4][3];
    unsigned int cnt[2];                       // candidate counts: 0=top, 1=bot
    unsigned int bt, cntGt, bb, cntLt;
    unsigned int sel[2][KSEL];
};

__device__ __forceinline__ float gelu_f(float v) {
    const float c = 0.7978845608028654f;
    float v3 = v * v * v;
    return 0.5f * v * (1.0f + tanhf(c * (v + 0.044715f * v3)));
}

__global__ __launch_bounds__(TPB, 4) void fused_gelu_gate(
    const float* __restrict__ x,
    const float* __restrict__ ema_mean,
    const float* __restrict__ ema_sq,
    const float* __restrict__ ema_out,
    const float* __restrict__ p_log_tau,
    const float* __restrict__ p_log_beta_up,
    const float* __restrict__ p_log_gamma,
    const float* __restrict__ p_logit_beta_fam,
    float* __restrict__ out)
{
    __shared__ SMem sh;
    const int tid = threadIdx.x;
    const int ln  = tid & 63;
    const int wv  = tid >> 6;
    const long long base = (long long)blockIdx.x * D_DIM;

    #pragma unroll
    for (int i = 0; i < NBIN / TPB; ++i) sh.u.hist[tid + i * TPB] = 0u;
    if (tid == 0) { sh.cnt[0] = 0u; sh.cnt[1] = 0u; }
    __syncthreads();

    const float tau      = expf(p_log_tau[0]);
    const float beta_up  = log1pf(expf(p_log_beta_up[0]));
    const float gma      = log1pf(expf(p_log_gamma[0]));
    const float beta_fam = 1.0f / (1.0f + expf(-p_logit_beta_fam[0]));

    float o_r[EPW], z_r[EPW];
    float s_o2 = 0.0f, s_dot = 0.0f, s_e2 = 0.0f;

    // ---- pass 1: load, gelu, z, sums, |z|-bit histogram ----
    #pragma unroll
    for (int i = 0; i < EPW / 4; ++i) {
        const int off = (i * TPB + tid) * 4;
        const float4 xv = *(const float4*)(x + base + off);
        const float4 mv = *(const float4*)(ema_mean + off);
        const float4 qv = *(const float4*)(ema_sq + off);
        const float4 ev = *(const float4*)(ema_out + off);
        const float xs[4] = {xv.x, xv.y, xv.z, xv.w};
        const float ms[4] = {mv.x, mv.y, mv.z, mv.w};
        const float qs[4] = {qv.x, qv.y, qv.z, qv.w};
        const float es[4] = {ev.x, ev.y, ev.z, ev.w};
        #pragma unroll
        for (int j = 0; j < 4; ++j) {
            const int e = i * 4 + j;
            const float xx = xs[j];
            const float mu = ms[j];
            float var = qs[j] - mu * mu;
            var = fmaxf(var, 1e-4f);
            const float zz = (xx - mu) / (sqrtf(var) + 1e-5f);
            const float og = gelu_f(xx);
            o_r[e] = og;
            z_r[e] = zz;
            s_o2  += og * og;
            s_dot += og * es[j];
            s_e2  += es[j] * es[j];
            const unsigned int bits = __float_as_uint(zz) & 0x7fffffffu;
            atomicAdd(&sh.u.hist[bits >> 21], 1u);
        }
    }

    // ---- block-reduce the three sums ----
    #pragma unroll
    for (int off = 32; off; off >>= 1) {
        s_o2  += __shfl_xor(s_o2, off);
        s_dot += __shfl_xor(s_dot, off);
        s_e2  += __shfl_xor(s_e2, off);
    }
    if (ln == 0) { sh.red[wv][0] = s_o2; sh.red[wv][1] = s_dot; sh.red[wv][2] = s_e2; }
    __syncthreads();   // also completes all histogram atomics

    const float t_o2  = sh.red[0][0] + sh.red[1][0] + sh.red[2][0] + sh.red[3][0];
    const float t_dot = sh.red[0][1] + sh.red[1][1] + sh.red[2][1] + sh.red[3][1];
    const float t_e2  = sh.red[0][2] + sh.red[1][2] + sh.red[2][2] + sh.red[3][2];

    // ---- wave0: suffix-scan histogram -> boundary bins + exact counts ----
    if (wv == 0) {
        unsigned int L = 0;
        #pragma unroll
        for (int j = 0; j < 16; ++j) L += sh.u.hist[ln * 16 + j];
        unsigned int v = L;
        #pragma unroll
        for (int off = 1; off < 64; off <<= 1) {
            const unsigned int t = __shfl_down(v, off);
            if (ln + off < 64) v += t;
        }
        const unsigned int S = v - L;            // count in bins strictly above this lane's range
        const unsigned int G = __shfl(v, 0);     // grand total (= D)
        const unsigned long long ballT = __ballot(v >= (unsigned int)KSEL);
        const int lt = 63 - __clzll((unsigned long long)ballT);
        if (ln == lt) {
            unsigned int run = S;
            for (int j = 15; j >= 0; --j) {
                const unsigned int rn = run + sh.u.hist[ln * 16 + j];
                if (run < (unsigned int)KSEL && rn >= (unsigned int)KSEL) {
                    sh.bt = (unsigned int)(ln * 16 + j);
                    sh.cntGt = run;
                }
                run = rn;
            }
        }
        const unsigned int PI = G - S;           // prefix including this lane's bins
        const unsigned long long ballB = __ballot(PI >= (unsigned int)KSEL);
        const int lb = __ffsll((unsigned long long)ballB) - 1;
        if (ln == lb) {
            unsigned int run = PI - L;
            for (int j = 0; j < 16; ++j) {
                const unsigned int rn = run + sh.u.hist[ln * 16 + j];
                if (run < (unsigned int)KSEL && rn >= (unsigned int)KSEL) {
                    sh.bb = (unsigned int)(ln * 16 + j);
                    sh.cntLt = run;
                }
                run = rn;
            }
        }
    }
    __syncthreads();

    const unsigned int bt = sh.bt, bb = sh.bb;
    const unsigned int rT = (unsigned int)KSEL - sh.cntGt;
    const unsigned int rB = (unsigned int)KSEL - sh.cntLt;

    // ---- collect: definite elements gated in-register; boundary-bin -> candidate lists ----
    // (overwrites hist storage via union — all hist reads are done)
    #pragma unroll
    for (int e = 0; e < EPW; ++e) {
        const int i = e >> 2, j = e & 3;
        const unsigned int d = ((unsigned int)(i * TPB + tid) << 2) | (unsigned int)j;
        const unsigned int bits = __float_as_uint(z_r[e]) & 0x7fffffffu;
        const unsigned int b = bits >> 21;
        if (b > bt) {
            float g = 1.0f + beta_up * tanhf(gma * z_r[e]);
            g = fminf(fmaxf(g, 0.1f), 8.0f);
            o_r[e] *= g;
        } else if (b == bt) {
            const unsigned int p = atomicAdd(&sh.cnt[0], 1u);
            if (p < CAP)
                sh.u.lists[p] = ((unsigned long long)bits << 32) | (unsigned long long)(~d);
        }
        if (b < bb) {
            o_r[e] *= beta_fam;
        } else if (b == bb) {
            const unsigned int p = atomicAdd(&sh.cnt[1], 1u);
            if (p < CAP)
                sh.u.lists[CAP + p] = ((unsigned long long)(~bits) << 32) | (unsigned long long)(~d);
        }
    }
    __syncthreads();

    // ---- resolve boundary candidates: wave0 -> top, wave1 -> bot ----
    if (wv < 2) {
        const int ph = wv;
        const unsigned int r = (ph == 0) ? rT : rB;
        unsigned int m = sh.cnt[ph];
        if (m > CAP) m = CAP;
        volatile unsigned long long* list =
            (volatile unsigned long long*)&sh.u.lists[ph * CAP];
        const int nq = (int)((m + 63u) >> 6);
        for (unsigned int it = 0; it < r; ++it) {
            unsigned long long best = 0ull;
            int bestp = -1;
            for (int q = 0; q < nq; ++q) {
                const unsigned int p = (unsigned int)ln + ((unsigned int)q << 6);
                if (p < m) {
                    const unsigned long long kk = list[p];
                    if (kk > best) { best = kk; bestp = (int)p; }
                }
            }
            unsigned long long k = best;
            #pragma unroll
            for (int off = 32; off; off >>= 1) {
                const unsigned long long o = __shfl_xor(k, off);
                if (o > k) k = o;
            }
            if (ln == 0) sh.sel[ph][it] = ~((unsigned int)(k & 0xffffffffu));
            if (bestp >= 0 && best == k) list[bestp] = 0ull;  // unique keys: one winner
        }
    }
    __syncthreads();

    // ---- apply selected boundary winners (owner thread matches its register slot) ----
    for (unsigned int it = 0; it < rT; ++it) {
        const unsigned int d = sh.sel[0][it];
        if (((d >> 2) & (TPB - 1)) == (unsigned int)tid) {
            const int e = (int)((d >> 10) << 2) + (int)(d & 3u);
            #pragma unroll
            for (int ee = 0; ee < EPW; ++ee) if (ee == e) {
                float g = 1.0f + beta_up * tanhf(gma * z_r[ee]);
                g = fminf(fmaxf(g, 0.1f), 8.0f);
                o_r[ee] *= g;
            }
        }
    }
    for (unsigned int it = 0; it < rB; ++it) {
        const unsigned int d = sh.sel[1][it];
        if (((d >> 2) & (TPB - 1)) == (unsigned int)tid) {
            const int e = (int)((d >> 10) << 2) + (int)(d & 3u);
            #pragma unroll
            for (int ee = 0; ee < EPW; ++ee) if (ee == e) o_r[ee] *= beta_fam;
        }
    }

    // ---- cosine gate + store ----
    const float on = sqrtf(t_o2);
    const float en = sqrtf(t_e2);
    float cs = t_dot / (fmaxf(on, 1e-12f) * fmaxf(en, 1e-12f));
    cs = fminf(fmaxf(cs, -1.0f), 1.0f);
    const float gc = expf(-tau * cs);

    #pragma unroll
    for (int i = 0; i < EPW / 4; ++i) {
        const int off = (i * TPB + tid) * 4;
        float4 ov;
        ov.x = o_r[i * 4 + 0] * gc;
        ov.y = o_r[i * 4 + 1] * gc;
        ov.z = o_r[i * 4 + 2] * gc;
        ov.w = o_r[i * 4 + 3] * gc;
        *(float4*)(out + base + off) = ov;
    }
}

extern "C" void kernel_launch(void* const* d_in, const int* in_sizes, int n_in,
                              void* d_out, int out_size, void* d_ws, size_t ws_size,
                              hipStream_t stream) {
    const float* x  = (const float*)d_in[0];
    const float* em = (const float*)d_in[1];
    const float* eq = (const float*)d_in[2];
    const float* eo = (const float*)d_in[3];
    const float* lt = (const float*)d_in[4];
    const float* lb = (const float*)d_in[5];
    const float* lg = (const float*)d_in[6];
    const float* lf = (const float*)d_in[7];
    float* o = (float*)d_out;
    const int rows = in_sizes[0] / D_DIM;
    fused_gelu_gate<<<dim3(rows), dim3(TPB), 0, stream>>>(x, em, eq, eo, lt, lb, lg, lf, o);
}

// Round 2
// 287.504 us; speedup vs baseline: 1.0321x; 1.0321x over previous
//
#include <hip/hip_runtime.h>
#include <stdint.h>

#define TPB   256
#define D_DIM 4096
#define EPW   16      // elements per thread = D/TPB
#define NBIN  1024
#define CAP   512
#define KSEL  16

// ws layout (floats)
#define WS_STDP 0
#define WS_INV  D_DIM
#define WS_SCAL (2*D_DIM)   // [0]=tau [1]=beta_up [2]=gamma [3]=beta_fam [4]=inv_e_norm

struct SMem {
    union {
        unsigned int hist[NBIN];               // 4 KB (pass 1)
        unsigned long long lists[2 * CAP];     // 8 KB (pass 2)
    } u;
    float red[4][2];
    unsigned int cnt[2];
    unsigned int bt, cntGt, bb, cntLt;
    unsigned int sel[2][KSEL];
};

__device__ __forceinline__ float fast_rcp(float v)  { return __builtin_amdgcn_rcpf(v); }
__device__ __forceinline__ float fast_exp2(float v) { return __builtin_amdgcn_exp2f(v); }

// gelu(x) = 0.5x(1+tanh(u)) = x * sigmoid(2u), u = c*(x + 0.044715 x^3)
// negq = -2u*log2e = x * (AN + BN*x^2);  gelu = x * rcp(1 + exp2(negq))
#define GELU_AN (-2.30220819f)   // -2c*log2e
#define GELU_BN (-0.10294331f)   // -2c*0.044715*log2e
#define TWO_LOG2E (2.8853900817779268f)

__device__ __forceinline__ float gelu_fast(float x) {
    float x2 = x * x;
    float s  = fmaf(x2, GELU_BN, GELU_AN);
    float nq = x * s;
    float ex = fast_exp2(nq);
    return x * fast_rcp(1.0f + ex);
}

// tanh(y) = 1 - 2*rcp(1 + exp2(y*2log2e)); arg passed pre-multiplied
__device__ __forceinline__ float tanh_fast_pm(float y2l) {
    float ex = fast_exp2(y2l);
    float r  = fast_rcp(1.0f + ex);
    return fmaf(-2.0f, r, 1.0f);
}

// ---- precompute: per-column stdp/inv + scalars (1 block) ----
__global__ __launch_bounds__(TPB) void precomp(
    const float* __restrict__ em, const float* __restrict__ eq,
    const float* __restrict__ eo,
    const float* __restrict__ lt, const float* __restrict__ lb,
    const float* __restrict__ lg, const float* __restrict__ lf,
    float* __restrict__ ws)
{
    __shared__ float red[4];
    const int tid = threadIdx.x;
    float e2 = 0.0f;
    for (int i = 0; i < D_DIM / TPB; ++i) {
        const int d = i * TPB + tid;
        const float mu  = em[d];
        const float mu2 = __fmul_rn(mu, mu);
        float var = __fsub_rn(eq[d], mu2);
        var = fmaxf(var, 1e-4f);
        const float stdp = __fadd_rn(sqrtf(var), 1e-5f);  // bit-identical to numpy std+EPS
        ws[WS_STDP + d] = stdp;
        ws[WS_INV + d]  = 1.0f / stdp;
        const float e = eo[d];
        e2 = fmaf(e, e, e2);
    }
    #pragma unroll
    for (int off = 32; off; off >>= 1) e2 += __shfl_xor(e2, off);
    if ((tid & 63) == 0) red[tid >> 6] = e2;
    __syncthreads();
    if (tid == 0) {
        const float t  = red[0] + red[1] + red[2] + red[3];
        const float en = sqrtf(t);
        ws[WS_SCAL + 0] = expf(lt[0]);
        ws[WS_SCAL + 1] = log1pf(expf(lb[0]));
        ws[WS_SCAL + 2] = log1pf(expf(lg[0]));
        ws[WS_SCAL + 3] = 1.0f / (1.0f + expf(-lf[0]));
        ws[WS_SCAL + 4] = 1.0f / fmaxf(en, 1e-12f);
    }
}

__global__ __launch_bounds__(TPB, 4) void fused_gelu_gate(
    const float* __restrict__ x,
    const float* __restrict__ ema_mean,
    const float* __restrict__ ema_out,
    const float* __restrict__ ws,
    float* __restrict__ out)
{
    __shared__ SMem sh;
    const int tid = threadIdx.x;
    const int ln  = tid & 63;
    const int wv  = tid >> 6;
    const long long base = (long long)blockIdx.x * D_DIM;

    #pragma unroll
    for (int i = 0; i < NBIN / TPB; ++i) sh.u.hist[tid + i * TPB] = 0u;
    if (tid == 0) { sh.cnt[0] = 0u; sh.cnt[1] = 0u; }
    __syncthreads();

    const float tau      = ws[WS_SCAL + 0];
    const float beta_up  = ws[WS_SCAL + 1];
    const float kg       = ws[WS_SCAL + 2] * TWO_LOG2E;  // gamma * 2log2e
    const float beta_fam = ws[WS_SCAL + 3];
    const float inv_en   = ws[WS_SCAL + 4];

    float x_r[EPW], o_r[EPW], z_r[EPW];
    float s_o2 = 0.0f, s_dot = 0.0f;

    // ---- pass 1: load, fast gelu, fast z, sums, |z|-bit histogram ----
    #pragma unroll
    for (int i = 0; i < EPW / 4; ++i) {
        const int off = (i * TPB + tid) * 4;
        const float4 xv = *(const float4*)(x + base + off);
        const float4 mv = *(const float4*)(ema_mean + off);
        const float4 iv = *(const float4*)(ws + WS_INV + off);
        const float4 ev = *(const float4*)(ema_out + off);
        const float xs[4] = {xv.x, xv.y, xv.z, xv.w};
        const float ms[4] = {mv.x, mv.y, mv.z, mv.w};
        const float is[4] = {iv.x, iv.y, iv.z, iv.w};
        const float es[4] = {ev.x, ev.y, ev.z, ev.w};
        #pragma unroll
        for (int j = 0; j < 4; ++j) {
            const int e = i * 4 + j;
            const float xx = xs[j];
            const float zz = (xx - ms[j]) * is[j];
            const float og = gelu_fast(xx);
            x_r[e] = xx;
            o_r[e] = og;
            z_r[e] = zz;
            s_o2  = fmaf(og, og, s_o2);
            s_dot = fmaf(og, es[j], s_dot);
            const unsigned int bits = __float_as_uint(zz) & 0x7fffffffu;
            atomicAdd(&sh.u.hist[bits >> 21], 1u);
        }
    }

    // ---- block-reduce the two sums ----
    #pragma unroll
    for (int off = 32; off; off >>= 1) {
        s_o2  += __shfl_xor(s_o2, off);
        s_dot += __shfl_xor(s_dot, off);
    }
    if (ln == 0) { sh.red[wv][0] = s_o2; sh.red[wv][1] = s_dot; }
    __syncthreads();   // also completes all histogram atomics

    const float t_o2  = sh.red[0][0] + sh.red[1][0] + sh.red[2][0] + sh.red[3][0];
    const float t_dot = sh.red[0][1] + sh.red[1][1] + sh.red[2][1] + sh.red[3][1];

    // ---- wave0: suffix-scan histogram -> boundary bins + exact counts ----
    if (wv == 0) {
        unsigned int L = 0;
        #pragma unroll
        for (int j = 0; j < 16; ++j) L += sh.u.hist[ln * 16 + j];
        unsigned int v = L;
        #pragma unroll
        for (int off = 1; off < 64; off <<= 1) {
            const unsigned int t = __shfl_down(v, off);
            if (ln + off < 64) v += t;
        }
        const unsigned int S = v - L;            // count in bins strictly above lane's range
        const unsigned int G = __shfl(v, 0);     // grand total (= D)
        const unsigned long long ballT = __ballot(v >= (unsigned int)KSEL);
        const int lt = 63 - __clzll((unsigned long long)ballT);
        if (ln == lt) {
            unsigned int run = S;
            for (int j = 15; j >= 0; --j) {
                const unsigned int rn = run + sh.u.hist[ln * 16 + j];
                if (run < (unsigned int)KSEL && rn >= (unsigned int)KSEL) {
                    sh.bt = (unsigned int)(ln * 16 + j);
                    sh.cntGt = run;
                }
                run = rn;
            }
        }
        const unsigned int PI = G - S;
        const unsigned long long ballB = __ballot(PI >= (unsigned int)KSEL);
        const int lb = __ffsll((unsigned long long)ballB) - 1;
        if (ln == lb) {
            unsigned int run = PI - L;
            for (int j = 0; j < 16; ++j) {
                const unsigned int rn = run + sh.u.hist[ln * 16 + j];
                if (run < (unsigned int)KSEL && rn >= (unsigned int)KSEL) {
                    sh.bb = (unsigned int)(ln * 16 + j);
                    sh.cntLt = run;
                }
                run = rn;
            }
        }
    }
    __syncthreads();

    const unsigned int bt = sh.bt, bb = sh.bb;
    const unsigned int rT = (unsigned int)KSEL - sh.cntGt;
    const unsigned int rB = (unsigned int)KSEL - sh.cntLt;

    // ---- collect: definite elements gated in-register; boundary bins -> candidate
    //      lists keyed by BIT-EXACT numpy z (precise var/std/div) ----
    #pragma unroll
    for (int e = 0; e < EPW; ++e) {
        const int i = e >> 2, j = e & 3;
        const unsigned int d = ((unsigned int)(i * TPB + tid) << 2) | (unsigned int)j;
        const unsigned int bits = __float_as_uint(z_r[e]) & 0x7fffffffu;
        const unsigned int b = bits >> 21;
        const bool isBt = (b == bt), isBb = (b == bb);
        unsigned int pb = 0u;
        if (isBt || isBb) {
            const float mu   = ema_mean[d];
            const float stdp = ws[WS_STDP + d];
            const float zp   = __fdiv_rn(__fsub_rn(x_r[e], mu), stdp);
            pb = __float_as_uint(zp) & 0x7fffffffu;
        }
        if (b > bt) {
            float g = fmaf(beta_up, tanh_fast_pm(z_r[e] * kg), 1.0f);
            g = fminf(fmaxf(g, 0.1f), 8.0f);
            o_r[e] *= g;
        } else if (isBt) {
            const unsigned int p = atomicAdd(&sh.cnt[0], 1u);
            if (p < CAP)
                sh.u.lists[p] = ((unsigned long long)pb << 32) | (unsigned long long)(~d);
        }
        if (b < bb) {
            o_r[e] *= beta_fam;
        } else if (isBb) {
            const unsigned int p = atomicAdd(&sh.cnt[1], 1u);
            if (p < CAP)
                sh.u.lists[CAP + p] = ((unsigned long long)(~pb) << 32) | (unsigned long long)(~d);
        }
    }
    __syncthreads();

    // ---- resolve boundary candidates: wave0 -> top, wave1 -> bot ----
    if (wv < 2) {
        const int ph = wv;
        const unsigned int r = (ph == 0) ? rT : rB;
        unsigned int m = sh.cnt[ph];
        if (m > CAP) m = CAP;
        volatile unsigned long long* list =
            (volatile unsigned long long*)&sh.u.lists[ph * CAP];
        const int nq = (int)((m + 63u) >> 6);
        for (unsigned int it = 0; it < r; ++it) {
            unsigned long long best = 0ull;
            int bestp = -1;
            for (int q = 0; q < nq; ++q) {
                const unsigned int p = (unsigned int)ln + ((unsigned int)q << 6);
                if (p < m) {
                    const unsigned long long kk = list[p];
                    if (kk > best) { best = kk; bestp = (int)p; }
                }
            }
            unsigned long long k = best;
            #pragma unroll
            for (int off = 32; off; off >>= 1) {
                const unsigned long long o = __shfl_xor(k, off);
                if (o > k) k = o;
            }
            if (ln == 0) sh.sel[ph][it] = ~((unsigned int)(k & 0xffffffffu));
            if (bestp >= 0 && best == k) list[bestp] = 0ull;
        }
    }
    __syncthreads();

    // ---- apply selected boundary winners ----
    for (unsigned int it = 0; it < rT; ++it) {
        const unsigned int d = sh.sel[0][it];
        if (((d >> 2) & (TPB - 1)) == (unsigned int)tid) {
            const int e = (int)((d >> 10) << 2) + (int)(d & 3u);
            #pragma unroll
            for (int ee = 0; ee < EPW; ++ee) if (ee == e) {
                float g = fmaf(beta_up, tanh_fast_pm(z_r[ee] * kg), 1.0f);
                g = fminf(fmaxf(g, 0.1f), 8.0f);
                o_r[ee] *= g;
            }
        }
    }
    for (unsigned int it = 0; it < rB; ++it) {
        const unsigned int d = sh.sel[1][it];
        if (((d >> 2) & (TPB - 1)) == (unsigned int)tid) {
            const int e = (int)((d >> 10) << 2) + (int)(d & 3u);
            #pragma unroll
            for (int ee = 0; ee < EPW; ++ee) if (ee == e) o_r[ee] *= beta_fam;
        }
    }

    // ---- cosine gate + store ----
    const float on = sqrtf(t_o2);
    float cs = (t_dot * inv_en) / fmaxf(on, 1e-12f);
    cs = fminf(fmaxf(cs, -1.0f), 1.0f);
    const float gc = expf(-tau * cs);

    #pragma unroll
    for (int i = 0; i < EPW / 4; ++i) {
        const int off = (i * TPB + tid) * 4;
        float4 ov;
        ov.x = o_r[i * 4 + 0] * gc;
        ov.y = o_r[i * 4 + 1] * gc;
        ov.z = o_r[i * 4 + 2] * gc;
        ov.w = o_r[i * 4 + 3] * gc;
        *(float4*)(out + base + off) = ov;
    }
}

extern "C" void kernel_launch(void* const* d_in, const int* in_sizes, int n_in,
                              void* d_out, int out_size, void* d_ws, size_t ws_size,
                              hipStream_t stream) {
    const float* x  = (const float*)d_in[0];
    const float* em = (const float*)d_in[1];
    const float* eq = (const float*)d_in[2];
    const float* eo = (const float*)d_in[3];
    const float* lt = (const float*)d_in[4];
    const float* lb = (const float*)d_in[5];
    const float* lg = (const float*)d_in[6];
    const float* lf = (const float*)d_in[7];
    float* o  = (float*)d_out;
    float* ws = (float*)d_ws;
    const int rows = in_sizes[0] / D_DIM;
    precomp<<<dim3(1), dim3(TPB), 0, stream>>>(em, eq, eo, lt, lb, lg, lf, ws);
    fused_gelu_gate<<<dim3(rows), dim3(TPB), 0, stream>>>(x, em, eo, ws, o);
}